// Round 17
// baseline (628.073 us; speedup 1.0000x reference)
//
#include <hip/hip_runtime.h>
#include <hip/hip_bf16.h>

#define S_ 577
#define B_ 16
#define H_ 16
#define DH 64
#define DM 1024
#define BH_ 256
#define DT_ 0.01f
#define BETA_ 4.0f
#define SCALE_ 0.125f
#define SPW2 37     // s-rows per wave (k_ode phase B, 16 waves)
#define PPW 19      // s-pairs per wave (k_ode phase A, 16 waves; 16*19=304)
#define L2E 1.44269504f
#define OFFV2 (4.0f * L2E)   // static exp2 offset, vanilla
#define OFFR2 (6.0f * L2E)   // static exp2 offset, resonance

typedef float f32x4 __attribute__((ext_vector_type(4)));
typedef short s16x8 __attribute__((ext_vector_type(8)));
typedef short s16x4 __attribute__((ext_vector_type(4)));

__device__ inline short f2bf(float x) {     // RNE f32->bf16 (PROVEN; v_cvt_pk_bf16_f32 is NOT RNE on gfx950 — r6/r12 failures)
    unsigned b = __builtin_bit_cast(unsigned, x);
    b += 0x7fffu + ((b >> 16) & 1u);
    return (short)(b >> 16);
}
__device__ inline float bf2f(short s) {
    unsigned u = ((unsigned)(unsigned short)s) << 16;
    return __builtin_bit_cast(float, u);
}
__device__ inline float ex2(float x) {     // 2^x (v_exp_f32 per ISA)
    float r;
    asm("v_exp_f32 %0, %1" : "=v"(r) : "v"(x));
    return r;
}
// vT bank-spreading swizzle (write & read use the same formula of row)
__device__ inline int vswz(int row) { return (((row >> 3) ^ row) & 7) << 3; }

// ---------------------------------------------------------------------------
// K1: per-(b,h) projections via MFMA. (unchanged, validated r13/r14)
// ---------------------------------------------------------------------------
__global__ __launch_bounds__(512) void k_proj(
    const float* __restrict__ x,
    const float* __restrict__ Wq, const float* __restrict__ bq,
    const float* __restrict__ Wk, const float* __restrict__ bk,
    const float* __restrict__ Wv, const float* __restrict__ bv,
    const float* __restrict__ Wom, const float* __restrict__ bom,
    const float* __restrict__ Wth, const float* __restrict__ bth,
    short* __restrict__ qh, short* __restrict__ kh, short* __restrict__ vh,
    float* __restrict__ om, float* __restrict__ zp)
{
    __shared__ __align__(16) short WqT[64*64], WkT[64*64], WvT[64*64];
    __shared__ __align__(16) short X_l[128*64];
    __shared__ float Wom_l[64], Wth_l[64];

    int bh = blockIdx.x, b = bh >> 4, h = bh & 15;
    int tid = threadIdx.x, w = tid >> 6, lane = tid & 63;
    int c = lane & 15, g = lane >> 4;

    {
        int d = tid >> 3, e0 = (tid & 7) << 3;
        const float* pq = Wq + (size_t)h*4096 + d*64 + e0;
        const float* pk = Wk + (size_t)h*4096 + d*64 + e0;
        const float* pv = Wv + (size_t)h*4096 + d*64 + e0;
        float4 q0 = *(const float4*)pq, q1 = *(const float4*)(pq + 4);
        float4 k0 = *(const float4*)pk, k1 = *(const float4*)(pk + 4);
        float4 v0 = *(const float4*)pv, v1 = *(const float4*)(pv + 4);
        float qv[8] = {q0.x,q0.y,q0.z,q0.w,q1.x,q1.y,q1.z,q1.w};
        float kv[8] = {k0.x,k0.y,k0.z,k0.w,k1.x,k1.y,k1.z,k1.w};
        float vv[8] = {v0.x,v0.y,v0.z,v0.w,v1.x,v1.y,v1.z,v1.w};
        #pragma unroll
        for (int j = 0; j < 8; ++j) {
            int e = e0 + j;
            int off = e*64 + (d ^ ((e&7)<<3));
            WqT[off] = f2bf(qv[j]);
            WkT[off] = f2bf(kv[j]);
            WvT[off] = f2bf(vv[j]);
        }
    }
    if (tid < 64) { Wom_l[tid] = Wom[h*64 + tid]; Wth_l[tid] = Wth[h*64 + tid]; }

    float bqv[4], bkv[4], bvv[4];
    #pragma unroll
    for (int e4 = 0; e4 < 4; ++e4) {
        bqv[e4] = bq[h*64 + e4*16 + c];
        bkv[e4] = bk[h*64 + e4*16 + c];
        bvv[e4] = bv[h*64 + e4*16 + c];
    }
    float bomv = bom[h], bthv = bth[h];

    const size_t xbase = (size_t)b*S_*DM + (size_t)h*DH;

    for (int t5 = 0; t5 < 5; ++t5) {
        int s0 = t5 * 128;
        __syncthreads();
        #pragma unroll
        for (int i = 0; i < 2; ++i) {
            int cid = tid + 512*i;
            int row = cid >> 3, ch = cid & 7;
            int s = s0 + row;
            float xv[8];
            if (s < S_) {
                const float* px = x + xbase + (size_t)s*DM + ch*8;
                float4 a0 = *(const float4*)px, a1 = *(const float4*)(px + 4);
                xv[0]=a0.x; xv[1]=a0.y; xv[2]=a0.z; xv[3]=a0.w;
                xv[4]=a1.x; xv[5]=a1.y; xv[6]=a1.z; xv[7]=a1.w;
                #pragma unroll
                for (int j = 0; j < 8; ++j) if (!isfinite(xv[j])) xv[j] = 0.f;
            } else {
                #pragma unroll
                for (int j = 0; j < 8; ++j) xv[j] = 0.f;
            }
            s16x8 xb;
            #pragma unroll
            for (int j = 0; j < 8; ++j) xb[j] = f2bf(xv[j]);
            *(s16x8*)&X_l[row*64 + ((ch*8) ^ ((row&7)<<3))] = xb;
            float po = 0.f, pt = 0.f;
            #pragma unroll
            for (int j = 0; j < 8; ++j) {
                po = fmaf(xv[j], Wom_l[ch*8 + j], po);
                pt = fmaf(xv[j], Wth_l[ch*8 + j], pt);
            }
            po += __shfl_xor(po, 1, 64); pt += __shfl_xor(pt, 1, 64);
            po += __shfl_xor(po, 2, 64); pt += __shfl_xor(pt, 2, 64);
            po += __shfl_xor(po, 4, 64); pt += __shfl_xor(pt, 4, 64);
            if (ch == 0 && s < S_) {
                om[(size_t)bh*S_ + s] = po + bomv;
                float si, co;
                sincosf(pt + bthv, &si, &co);
                reinterpret_cast<float2*>(zp)[(size_t)bh*S_ + s] = make_float2(co, si);
            }
        }
        __syncthreads();
        int arow = w*16 + c;
        s16x8 xa0 = *(const s16x8*)&X_l[arow*64 + ((g*8)      ^ ((arow&7)<<3))];
        s16x8 xa1 = *(const s16x8*)&X_l[arow*64 + ((g*8 + 32) ^ ((arow&7)<<3))];

        const short* WT[3] = {WqT, WkT, WvT};
        short* dst[3] = {qh, kh, vh};
        #pragma unroll
        for (int o = 0; o < 3; ++o) {
            f32x4 acc[4];
            #pragma unroll
            for (int e4 = 0; e4 < 4; ++e4) {
                int brow = e4*16 + c;
                s16x8 b0 = *(const s16x8*)&WT[o][brow*64 + ((g*8)      ^ ((brow&7)<<3))];
                s16x8 b1 = *(const s16x8*)&WT[o][brow*64 + ((g*8 + 32) ^ ((brow&7)<<3))];
                f32x4 a = {0.f,0.f,0.f,0.f};
                a = __builtin_amdgcn_mfma_f32_16x16x32_bf16(xa0, b0, a, 0, 0, 0);
                a = __builtin_amdgcn_mfma_f32_16x16x32_bf16(xa1, b1, a, 0, 0, 0);
                acc[e4] = a;
            }
            float* bias = (o == 0) ? bqv : (o == 1) ? bkv : bvv;
            #pragma unroll
            for (int r = 0; r < 4; ++r) {
                int s = s0 + w*16 + 4*g + r;
                if (s < S_) {
                    s16x4 pk;
                    pk[0] = f2bf(acc[0][r] + bias[0]);
                    pk[1] = f2bf(acc[1][r] + bias[1]);
                    pk[2] = f2bf(acc[2][r] + bias[2]);
                    pk[3] = f2bf(acc[3][r] + bias[3]);
                    *(s16x4*)(dst[o] + (size_t)bh*S_*DH + (size_t)s*DH + c*4) = pk;
                }
            }
        }
    }
}

// ---------------------------------------------------------------------------
// K2: Stuart-Landau ODE, 16 waves, register-resident k/q.
// amdgpu_waves_per_eu(4,4): min AND max 4 waves/EU (exactly our occupancy:
// grid = 1 block/CU, 16 waves) -> register budget 512/4 = 128 VGPR.
// launch_bounds' 2nd arg alone (min-only) left the allocator targeting
// 8 waves/EU -> 64-VGPR cap -> 1.2 GB scratch spill (r3/r15/r16 evidence).
// ---------------------------------------------------------------------------
__global__ __launch_bounds__(1024) __attribute__((amdgpu_waves_per_eu(4, 4)))
void k_ode(
    const short* __restrict__ qh, const short* __restrict__ kh,
    const float* __restrict__ om,
    const float* __restrict__ mu, const float* __restrict__ kappa,
    const float* __restrict__ alpha, const int* __restrict__ nsim,
    float* __restrict__ zp)
{
    __shared__ __align__(16) float2 z_l[608];      // 4864 B (padded)
    __shared__ __align__(16) float2 z1_l[608];     // 4864 B
    __shared__ __align__(16) float2 kz_s[8][64];   // 4096 B
    __shared__ __align__(16) float2 kzv[64];       // 512 B

    int bh = blockIdx.x, h = bh & 15;
    int tid = threadIdx.x, w = tid >> 6, lane = tid & 63;
    const short* kg = kh + (size_t)bh*S_*DH;
    const short* qg = qh + (size_t)bh*S_*DH;
    float2* zpg = reinterpret_cast<float2*>(zp) + (size_t)bh*S_;
    const float* omg = om + (size_t)bh*S_;

    for (int i = tid; i < 608; i += 1024) {
        z_l[i] = (i < S_) ? zpg[i] : make_float2(0.f, 0.f);
        z1_l[i] = make_float2(0.f, 0.f);
    }

    // --- k into registers: pair sp = w*19 + j; k_reg[j] = pack(k[2sp][lane], k[2sp+1][lane])
    int sp0 = w * PPW;
    unsigned k_reg[PPW];
    #pragma unroll
    for (int j = 0; j < PPW; ++j) {
        int sA = 2*(sp0 + j), sB = sA + 1;
        unsigned lo = (sA < S_) ? (unsigned)(unsigned short)kg[(size_t)sA*DH + lane] : 0u;
        unsigned hi = (sB < S_) ? (unsigned)(unsigned short)kg[(size_t)sB*DH + lane] : 0u;
        k_reg[j] = lo | (hi << 16);
    }
    // --- q into registers: rows s0 + i8 + 8m (m=0..4), e-chunk d0..d0+7
    int i8 = lane >> 3, d0 = (lane & 7) << 3;
    int s0 = w * SPW2;
    s16x8 q_reg[5];
    float om_r[5];
    #pragma unroll
    for (int m2 = 0; m2 < 5; ++m2) {
        int li = i8 + 8*m2, s = s0 + li;
        bool ok = (li < SPW2) && (s < S_);
        s16x8 v = {0,0,0,0,0,0,0,0};
        if (ok) v = *(const s16x8*)(qg + (size_t)s*DH + d0);
        q_reg[m2] = v;
        om_r[m2] = ok ? omg[s] : 0.f;
    }
    float ca = cosf(alpha[h]), sa = sinf(alpha[h]);
    float muv = mu[h];
    float cc = kappa[h] * SCALE_ / (float)S_;
    int NT = nsim[0];
    __syncthreads();

    for (int ev = 0; ev < 2*NT; ++ev) {
        bool second = ev & 1;
        const float2* zin = second ? z1_l : z_l;
        // phase A: partial kz[e=lane] over this wave's 19 pairs (k in regs;
        // z reads are wave-uniform broadcast b128)
        float ar = 0.f, ai = 0.f, br = 0.f, bi = 0.f;
        #pragma unroll
        for (int j = 0; j < PPW; ++j) {
            float4 zz = *reinterpret_cast<const float4*>(&zin[2*(sp0 + j)]);
            float klo = __builtin_bit_cast(float, k_reg[j] << 16);
            float khi = __builtin_bit_cast(float, k_reg[j] & 0xffff0000u);
            ar = fmaf(klo, zz.x, ar); ai = fmaf(klo, zz.y, ai);
            br = fmaf(khi, zz.z, br); bi = fmaf(khi, zz.w, bi);
        }
        float2 part = make_float2(ar + br, ai + bi);
        if (w < 8) kz_s[w][lane] = part;
        __syncthreads();
        if (w >= 8) {
            float2 t = kz_s[w - 8][lane];
            t.x += part.x; t.y += part.y;
            kz_s[w - 8][lane] = t;
        }
        __syncthreads();
        // every lane computes kz[e=lane], writes kzv[lane]; then reads its
        // 8 needed entries as broadcast b128 (same-wave RAW only)
        {
            float sr = 0.f, si = 0.f;
            #pragma unroll
            for (int w2 = 0; w2 < 8; ++w2) {
                float2 t = kz_s[w2][lane];
                sr += t.x; si += t.y;
            }
            kzv[lane] = make_float2(sr, si);
        }
        float4 kza = *reinterpret_cast<const float4*>(&kzv[d0]);
        float4 kzb = *reinterpret_cast<const float4*>(&kzv[d0 + 2]);
        float4 kzc = *reinterpret_cast<const float4*>(&kzv[d0 + 4]);
        float4 kzd = *reinterpret_cast<const float4*>(&kzv[d0 + 6]);
        float kzr[8] = {kza.x, kza.z, kzb.x, kzb.z, kzc.x, kzc.z, kzd.x, kzd.z};
        float kzi[8] = {kza.y, kza.w, kzb.y, kzb.w, kzc.y, kzc.w, kzd.y, kzd.w};
        // phase B: u_s = cc * q_s . kz (q in regs); Stuart-Landau + Heun
        #pragma unroll
        for (int m2 = 0; m2 < 5; ++m2) {
            int li = i8 + 8*m2, s = s0 + li;
            bool act = (li < SPW2) && (s < S_);
            float ur = 0.f, ui = 0.f;
            #pragma unroll
            for (int j = 0; j < 8; ++j) {
                float qf = bf2f(q_reg[m2][j]);
                ur = fmaf(qf, kzr[j], ur);
                ui = fmaf(qf, kzi[j], ui);
            }
            #pragma unroll
            for (int mm = 1; mm < 8; mm <<= 1) {
                ur += __shfl_xor(ur, mm, 64);
                ui += __shfl_xor(ui, mm, 64);
            }
            if (act && d0 == 0) {
                float2 z = zin[s];
                float urc = cc*ur, uic = cc*ui;
                float cr = ca*urc + sa*uic;
                float ci = ca*uic - sa*urc;
                float g = muv - (z.x*z.x + z.y*z.y);
                float dr = fmaf(g, z.x, fmaf(-om_r[m2], z.y, cr));
                float di = fmaf(g, z.y, fmaf( om_r[m2], z.x, ci));
                float2 zb = z_l[s];
                if (!second) {
                    z1_l[s] = make_float2(fmaf(DT_, dr, z.x), fmaf(DT_, di, z.y));
                    z_l[s]  = make_float2(fmaf(0.5f*DT_, dr, zb.x), fmaf(0.5f*DT_, di, zb.y));
                } else {
                    z_l[s]  = make_float2(fmaf(0.5f*DT_, dr, zb.x), fmaf(0.5f*DT_, di, zb.y));
                }
            }
        }
        __syncthreads();
    }
    for (int i = tid; i < S_; i += 1024) zpg[i] = z_l[i];
}

// ---------------------------------------------------------------------------
// K3: dual flash attention. (unchanged, validated r13/r14)
// ---------------------------------------------------------------------------
__global__ __launch_bounds__(512) void k_attn(
    const short* __restrict__ qh, const short* __restrict__ kh,
    const short* __restrict__ vh, const float* __restrict__ zp,
    const float* __restrict__ mix_logit, const float* __restrict__ band_logits,
    short* __restrict__ yh)
{
    __shared__ short q_l[128*64];     // q (prologue+hoist), then P0 slices
    __shared__ short P1_l[8][1024];   // resonance-branch P
    __shared__ short k_l2[64*64];
    __shared__ short vT_l[64*64];
    __shared__ float2 zs_l[128];
    __shared__ float2 zt_l[64];

    int blk = blockIdx.x;
    int bh = blk / 5, rc = blk - bh*5;
    int b = bh >> 4, h = bh & 15;
    int r0 = rc * 128;
    int tid = threadIdx.x, w = tid >> 6, lane = tid & 63;
    int c = lane & 15, g = lane >> 4;

    const short* qg = qh + (size_t)bh*S_*DH;
    const short* kg = kh + (size_t)bh*S_*DH;
    const short* vg = vh + (size_t)bh*S_*DH;
    const float2* zpg = (const float2*)zp + (size_t)bh*S_;

    #pragma unroll
    for (int i = 0; i < 2; ++i) {
        int cid = tid + 512*i;
        int row = cid >> 3, ch = cid & 7;
        int s = r0 + row;
        s16x8 val = {0,0,0,0,0,0,0,0};
        if (s < S_) val = *(const s16x8*)(qg + (size_t)s*DH + ch*8);
        *(s16x8*)&q_l[row*64 + ((ch*8) ^ ((row&7)<<3))] = val;
    }
    if (tid < 128) {
        float2 z = (r0 + tid < S_) ? zpg[r0 + tid] : make_float2(0.f,0.f);
        zs_l[tid] = make_float2(z.x*(BETA_*L2E), z.y*(BETA_*L2E));
    }
    __syncthreads();

    s16x8 qf0, qf1;
    {
        int row = w*16 + c;
        qf0 = *(const s16x8*)&q_l[row*64 + ((g*8)      ^ ((row&7)<<3))];
        qf1 = *(const s16x8*)&q_l[row*64 + ((g*8 + 32) ^ ((row&7)<<3))];
    }
    float2 zsr[4];
    #pragma unroll
    for (int r = 0; r < 4; ++r) zsr[r] = zs_l[w*16 + (g<<2) + r];

    f32x4 accv[4], accr[4];
    float Z_v[4], Z_r[4];
    #pragma unroll
    for (int i = 0; i < 4; ++i) {
        accv[i] = (f32x4){0.f,0.f,0.f,0.f};
        accr[i] = (f32x4){0.f,0.f,0.f,0.f};
        Z_v[i] = 0.f; Z_r[i] = 0.f;
    }

    short* P0 = &q_l[w << 10];   // per-wave 1024-short slice (dead q space)
    short* P1 = &P1_l[w][0];

    for (int tt = 0; tt < 10; ++tt) {
        int t0g = tt * 64;
        __syncthreads();
        {   // stage k tile (stored-e space, same as q)
            int row = tid >> 3, ch = tid & 7;
            int t = t0g + row;
            s16x8 val = {0,0,0,0,0,0,0,0};
            if (t < S_) val = *(const s16x8*)(kg + (size_t)t*DH + ch*8);
            *(s16x8*)&k_l2[row*64 + ((ch*8) ^ ((row&7)<<3))] = val;
        }
        {   // stage v: stored col -> TRUE e row, perm'd k-cols, vswz banks
            int tloc = tid >> 3, d0 = (tid & 7) << 3;
            int pt = ((tloc & 15) << 2) + (tloc >> 4);   // perm(t)
            s16x8 vv = {0,0,0,0,0,0,0,0};
            if (t0g + tloc < S_) vv = *(const s16x8*)(vg + (size_t)(t0g+tloc)*DH + d0);
            #pragma unroll
            for (int j = 0; j < 8; ++j) {
                int sc = d0 + j;                          // stored col
                int te = ((sc & 3) << 4) + (sc >> 2);     // true e
                vT_l[te*64 + (pt ^ vswz(te))] = vv[j];
            }
        }
        if (tid < 64) zt_l[tid] = (t0g + tid < S_) ? zpg[t0g + tid] : make_float2(0.f,0.f);
        __syncthreads();

        // ---- scores (exp2 domain)
        f32x4 sv[4], sr4[4];
        #pragma unroll
        for (int sub = 0; sub < 4; ++sub) {
            int row = sub*16 + c;
            s16x8 kf0 = *(const s16x8*)&k_l2[row*64 + ((g*8)      ^ ((c&7)<<3))];
            s16x8 kf1 = *(const s16x8*)&k_l2[row*64 + ((g*8 + 32) ^ ((c&7)<<3))];
            f32x4 a = {0.f,0.f,0.f,0.f};
            a = __builtin_amdgcn_mfma_f32_16x16x32_bf16(qf0, kf0, a, 0, 0, 0);
            a = __builtin_amdgcn_mfma_f32_16x16x32_bf16(qf1, kf1, a, 0, 0, 0);
            sv[sub] = a * (SCALE_ * L2E) - OFFV2;
        }
        #pragma unroll
        for (int sub = 0; sub < 4; ++sub) {
            float2 zt = zt_l[sub*16 + c];
            #pragma unroll
            for (int r = 0; r < 4; ++r)
                sr4[sub][r] = fmaf(zsr[r].x, zt.x, fmaf(zsr[r].y, zt.y, -OFFR2));
        }
        if (t0g + 64 > S_) {    // uniform: only the tail tile
            #pragma unroll
            for (int sub = 0; sub < 4; ++sub)
                if (t0g + sub*16 + c >= S_) {
                    #pragma unroll
                    for (int r = 0; r < 4; ++r) { sv[sub][r] = -1e30f; sr4[sub][r] = -1e30f; }
                }
        }

        // ---- softmax numerators: exp2 + RNE f2bf, one b64 store per (r,branch)
        #pragma unroll
        for (int r = 0; r < 4; ++r) {
            int sl = (g<<2) + r;
            int pco = sl*64 + ((c*4) ^ ((sl&7)<<3));   // perm(t)=c*4+sub cols
            s16x4 pk0, pk1;
            float sumv = 0.f, sumr = 0.f;
            #pragma unroll
            for (int sub = 0; sub < 4; ++sub) {
                float pv = ex2(sv[sub][r]);
                float pr = ex2(sr4[sub][r]);
                sumv += pv; sumr += pr;
                pk0[sub] = f2bf(pv);
                pk1[sub] = f2bf(pr);
            }
            *(s16x4*)&P0[pco] = pk0;
            *(s16x4*)&P1[pco] = pk1;
            Z_v[r] += sumv;
            Z_r[r] += sumr;
        }

        // ---- PV: read both branches (read-once per tile)
        #pragma unroll
        for (int hh = 0; hh < 2; ++hh) {
            int kc = g*8 + 32*hh;
            int po = c*64 + (kc ^ ((c&7)<<3));
            s16x8 pa_v = *(const s16x8*)&P0[po];
            s16x8 pa_r = *(const s16x8*)&P1[po];
            #pragma unroll
            for (int d = 0; d < 4; ++d) {
                int row = d*16 + c;
                s16x8 vf = *(const s16x8*)&vT_l[row*64 + (kc ^ vswz(row))];
                accv[d] = __builtin_amdgcn_mfma_f32_16x16x32_bf16(pa_v, vf, accv[d], 0, 0, 0);
                accr[d] = __builtin_amdgcn_mfma_f32_16x16x32_bf16(pa_r, vf, accr[d], 0, 0, 0);
            }
        }
    }

    // ---- single final Z reduce over the 16-lane c-group
    #pragma unroll
    for (int mm = 1; mm < 16; mm <<= 1) {
        #pragma unroll
        for (int r = 0; r < 4; ++r) {
            Z_v[r] += __shfl_xor(Z_v[r], mm, 64);
            Z_r[r] += __shfl_xor(Z_r[r], mm, 64);
        }
    }

    float mixv = 1.f/(1.f + __expf(-mix_logit[h]));
    #pragma unroll
    for (int d = 0; d < 4; ++d) {
        float gate = 1.f/(1.f + __expf(-band_logits[h*4 + d]));
        #pragma unroll
        for (int r = 0; r < 4; ++r) {
            int s = r0 + w*16 + (g<<2) + r;
            if (s < S_) {
                float val = mixv*gate*(accr[d][r]/Z_r[r]) + (1.f-mixv)*(accv[d][r]/Z_v[r]);
                yh[(size_t)b*S_*DM + (size_t)s*DM + h*DH + d*16 + c] = f2bf(val);
            }
        }
    }
}

// ---------------------------------------------------------------------------
// K4b: Wo (f32 [k][n]) -> WoT (bf16 [n][k]) tile transpose
// ---------------------------------------------------------------------------
__global__ __launch_bounds__(256) void k_cvt(
    const float* __restrict__ Wo, short* __restrict__ Bt)
{
    __shared__ short tl[64][65];
    int k0 = blockIdx.x * 64, n0 = blockIdx.y * 64;
    int tid = threadIdx.x;
    int r = tid >> 2, cb = (tid & 3) * 16;
    #pragma unroll
    for (int j4 = 0; j4 < 4; ++j4) {
        float4 v = *reinterpret_cast<const float4*>(Wo + (size_t)(k0+r)*1024 + n0 + cb + j4*4);
        tl[r][cb + j4*4 + 0] = f2bf(v.x);
        tl[r][cb + j4*4 + 1] = f2bf(v.y);
        tl[r][cb + j4*4 + 2] = f2bf(v.z);
        tl[r][cb + j4*4 + 3] = f2bf(v.w);
    }
    __syncthreads();
    s16x8 v0, v1;
    #pragma unroll
    for (int j = 0; j < 8; ++j) { v0[j] = tl[cb+j][r]; v1[j] = tl[cb+8+j][r]; }
    *(s16x8*)(Bt + (size_t)(n0+r)*1024 + k0 + cb)     = v0;
    *(s16x8*)(Bt + (size_t)(n0+r)*1024 + k0 + cb + 8) = v1;
}

// ---------------------------------------------------------------------------
// K4: out = y(9232x1024 bf16) @ Wo + bo, MFMA 16x16x32 bf16, 128x128 tile.
// ---------------------------------------------------------------------------
__global__ __launch_bounds__(256) void k_gemm(
    const short* __restrict__ A, const short* __restrict__ Bt,
    const float* __restrict__ bias, float* __restrict__ out)
{
    const int M = B_ * S_;
    __shared__ short A_l[128*64];
    __shared__ short B_l[128*64];
    int m0 = blockIdx.x * 128, n0 = blockIdx.y * 128;
    int tid = threadIdx.x, w = tid >> 6, lane = tid & 63;
    int c = lane & 15, g = lane >> 4;
    int mb = (w & 1) * 64, nb = (w >> 1) * 64;
    f32x4 acc[4][4];
    #pragma unroll
    for (int i = 0; i < 4; ++i)
        #pragma unroll
        for (int j = 0; j < 4; ++j) acc[i][j] = (f32x4){0.f,0.f,0.f,0.f};
    for (int k0 = 0; k0 < 1024; k0 += 64) {
        __syncthreads();
        #pragma unroll
        for (int i = 0; i < 4; ++i) {
            int cid = tid + 256*i;
            int row = cid >> 3, ch = cid & 7;
            int m = m0 + row;
            s16x8 av = {0,0,0,0,0,0,0,0};
            if (m < M) av = *(const s16x8*)(A + (size_t)m*1024 + k0 + ch*8);
            *(s16x8*)&A_l[row*64 + ((ch*8) ^ ((row&7)<<3))] = av;
            s16x8 bv = *(const s16x8*)(Bt + (size_t)(n0+row)*1024 + k0 + ch*8);
            *(s16x8*)&B_l[row*64 + ((ch*8) ^ ((row&7)<<3))] = bv;
        }
        __syncthreads();
        s16x8 af[4][2], bf[4][2];
        #pragma unroll
        for (int i = 0; i < 4; ++i) {
            int ra = mb + i*16 + c;
            af[i][0] = *(const s16x8*)&A_l[ra*64 + ((g*8)      ^ ((c&7)<<3))];
            af[i][1] = *(const s16x8*)&A_l[ra*64 + ((g*8 + 32) ^ ((c&7)<<3))];
            int rb = nb + i*16 + c;
            bf[i][0] = *(const s16x8*)&B_l[rb*64 + ((g*8)      ^ ((c&7)<<3))];
            bf[i][1] = *(const s16x8*)&B_l[rb*64 + ((g*8 + 32) ^ ((c&7)<<3))];
        }
        #pragma unroll
        for (int i = 0; i < 4; ++i)
            #pragma unroll
            for (int j = 0; j < 4; ++j) {
                acc[i][j] = __builtin_amdgcn_mfma_f32_16x16x32_bf16(af[i][0], bf[j][0], acc[i][j], 0, 0, 0);
                acc[i][j] = __builtin_amdgcn_mfma_f32_16x16x32_bf16(af[i][1], bf[j][1], acc[i][j], 0, 0, 0);
            }
    }
    #pragma unroll
    for (int j = 0; j < 4; ++j) {
        float bv = bias[n0 + nb + j*16 + c];
        #pragma unroll
        for (int i = 0; i < 4; ++i)
            #pragma unroll
            for (int r = 0; r < 4; ++r) {
                int m = m0 + mb + i*16 + 4*g + r;
                if (m < M) out[(size_t)m*1024 + n0 + nb + j*16 + c] = acc[i][j][r] + bv;
            }
    }
}

// ---------------------------------------------------------------------------
extern "C" void kernel_launch(void* const* d_in, const int* in_sizes, int n_in,
                              void* d_out, int out_size, void* d_ws, size_t ws_size,
                              hipStream_t stream)
{
    const float* x   = (const float*)d_in[0];
    const float* Wq  = (const float*)d_in[1];
    const float* bq  = (const float*)d_in[2];
    const float* Wk  = (const float*)d_in[3];
    const float* bk  = (const float*)d_in[4];
    const float* Wv  = (const float*)d_in[5];
    const float* bv  = (const float*)d_in[6];
    const float* Wom = (const float*)d_in[7];
    const float* bom = (const float*)d_in[8];
    const float* Wth = (const float*)d_in[9];
    const float* bth = (const float*)d_in[10];
    const float* mu  = (const float*)d_in[11];
    const float* kap = (const float*)d_in[12];
    const float* alp = (const float*)d_in[13];
    const float* mix = (const float*)d_in[14];
    const float* bl  = (const float*)d_in[15];
    const float* Wo  = (const float*)d_in[16];
    const float* bo  = (const float*)d_in[17];
    const int* nsim  = (const int*)d_in[18];

    float* ws = (float*)d_ws;
    const size_t QKV = (size_t)BH_ * S_ * DH;    // 9,453,568
    float* qf = ws;                               // slot A (aliased below)
    float* kf = qf + QKV;                         // slot B (aliased below)
    float* om = kf + QKV;                         // BH*S
    float* zp = om + (size_t)BH_*S_;              // 2*BH*S
    short* qh = (short*)(zp + (size_t)2*BH_*S_);  // bf16 q (e-permuted)
    short* kh = qh + QKV;                         // bf16 k (e-permuted)
    short* vh = kh + QKV;                         // bf16 v (e-permuted)
    short* yh  = (short*)qf;                      // bf16 y (attn out)
    short* WoT = (short*)kf;                      // bf16 Wo^T
    float* outf = (float*)d_out;

    k_proj<<<BH_, 512, 0, stream>>>(x, Wq, bq, Wk, bk, Wv, bv, Wom, bom, Wth, bth,
                                    qh, kh, vh, om, zp);
    k_ode<<<BH_, 1024, 0, stream>>>(qh, kh, om, mu, kap, alp, nsim, zp);
    k_cvt<<<dim3(16,16), 256, 0, stream>>>(Wo, WoT);
    k_attn<<<BH_*5, 512, 0, stream>>>(qh, kh, vh, zp, mix, bl, yh);
    dim3 gg(73, 8);
    k_gemm<<<gg, 256, 0, stream>>>(yh, WoT, bo, outf);
}

// Round 18
// 314.367 us; speedup vs baseline: 1.9979x; 1.9979x over previous
//
#include <hip/hip_runtime.h>
#include <hip/hip_bf16.h>

#define S_ 577
#define B_ 16
#define H_ 16
#define DH 64
#define DM 1024
#define BH_ 256
#define DT_ 0.01f
#define BETA_ 4.0f
#define SCALE_ 0.125f
#define SPP 292     // s-pairs in k_ode phase A
#define KPR 293     // k_ode kp row stride (odd -> conflict-free)
#define SPW2 37     // s-rows per wave (k_ode phase B, 16 waves)
#define L2E 1.44269504f
#define OFFV2 (4.0f * L2E)   // static exp2 offset, vanilla
#define OFFR2 (6.0f * L2E)   // static exp2 offset, resonance

typedef float f32x4 __attribute__((ext_vector_type(4)));
typedef short s16x8 __attribute__((ext_vector_type(8)));
typedef short s16x4 __attribute__((ext_vector_type(4)));

__device__ inline short f2bf(float x) {     // RNE f32->bf16 (PROVEN; v_cvt_pk_bf16_f32 is NOT RNE on gfx950 — r6/r12 failures)
    unsigned b = __builtin_bit_cast(unsigned, x);
    b += 0x7fffu + ((b >> 16) & 1u);
    return (short)(b >> 16);
}
__device__ inline float bf2f(short s) {
    unsigned u = ((unsigned)(unsigned short)s) << 16;
    return __builtin_bit_cast(float, u);
}
__device__ inline float ex2(float x) {     // 2^x (v_exp_f32 per ISA)
    float r;
    asm("v_exp_f32 %0, %1" : "=v"(r) : "v"(x));
    return r;
}
// vT bank-spreading swizzle (write & read use the same formula of row)
__device__ inline int vswz(int row) { return (((row >> 3) ^ row) & 7) << 3; }

// ---------------------------------------------------------------------------
// K1: per-(b,h) projections via MFMA. (unchanged, validated r13/r14)
// ---------------------------------------------------------------------------
__global__ __launch_bounds__(512) void k_proj(
    const float* __restrict__ x,
    const float* __restrict__ Wq, const float* __restrict__ bq,
    const float* __restrict__ Wk, const float* __restrict__ bk,
    const float* __restrict__ Wv, const float* __restrict__ bv,
    const float* __restrict__ Wom, const float* __restrict__ bom,
    const float* __restrict__ Wth, const float* __restrict__ bth,
    short* __restrict__ qh, short* __restrict__ kh, short* __restrict__ vh,
    float* __restrict__ om, float* __restrict__ zp)
{
    __shared__ __align__(16) short WqT[64*64], WkT[64*64], WvT[64*64];
    __shared__ __align__(16) short X_l[128*64];
    __shared__ float Wom_l[64], Wth_l[64];

    int bh = blockIdx.x, b = bh >> 4, h = bh & 15;
    int tid = threadIdx.x, w = tid >> 6, lane = tid & 63;
    int c = lane & 15, g = lane >> 4;

    {
        int d = tid >> 3, e0 = (tid & 7) << 3;
        const float* pq = Wq + (size_t)h*4096 + d*64 + e0;
        const float* pk = Wk + (size_t)h*4096 + d*64 + e0;
        const float* pv = Wv + (size_t)h*4096 + d*64 + e0;
        float4 q0 = *(const float4*)pq, q1 = *(const float4*)(pq + 4);
        float4 k0 = *(const float4*)pk, k1 = *(const float4*)(pk + 4);
        float4 v0 = *(const float4*)pv, v1 = *(const float4*)(pv + 4);
        float qv[8] = {q0.x,q0.y,q0.z,q0.w,q1.x,q1.y,q1.z,q1.w};
        float kv[8] = {k0.x,k0.y,k0.z,k0.w,k1.x,k1.y,k1.z,k1.w};
        float vv[8] = {v0.x,v0.y,v0.z,v0.w,v1.x,v1.y,v1.z,v1.w};
        #pragma unroll
        for (int j = 0; j < 8; ++j) {
            int e = e0 + j;
            int off = e*64 + (d ^ ((e&7)<<3));
            WqT[off] = f2bf(qv[j]);
            WkT[off] = f2bf(kv[j]);
            WvT[off] = f2bf(vv[j]);
        }
    }
    if (tid < 64) { Wom_l[tid] = Wom[h*64 + tid]; Wth_l[tid] = Wth[h*64 + tid]; }

    float bqv[4], bkv[4], bvv[4];
    #pragma unroll
    for (int e4 = 0; e4 < 4; ++e4) {
        bqv[e4] = bq[h*64 + e4*16 + c];
        bkv[e4] = bk[h*64 + e4*16 + c];
        bvv[e4] = bv[h*64 + e4*16 + c];
    }
    float bomv = bom[h], bthv = bth[h];

    const size_t xbase = (size_t)b*S_*DM + (size_t)h*DH;

    for (int t5 = 0; t5 < 5; ++t5) {
        int s0 = t5 * 128;
        __syncthreads();
        #pragma unroll
        for (int i = 0; i < 2; ++i) {
            int cid = tid + 512*i;
            int row = cid >> 3, ch = cid & 7;
            int s = s0 + row;
            float xv[8];
            if (s < S_) {
                const float* px = x + xbase + (size_t)s*DM + ch*8;
                float4 a0 = *(const float4*)px, a1 = *(const float4*)(px + 4);
                xv[0]=a0.x; xv[1]=a0.y; xv[2]=a0.z; xv[3]=a0.w;
                xv[4]=a1.x; xv[5]=a1.y; xv[6]=a1.z; xv[7]=a1.w;
                #pragma unroll
                for (int j = 0; j < 8; ++j) if (!isfinite(xv[j])) xv[j] = 0.f;
            } else {
                #pragma unroll
                for (int j = 0; j < 8; ++j) xv[j] = 0.f;
            }
            s16x8 xb;
            #pragma unroll
            for (int j = 0; j < 8; ++j) xb[j] = f2bf(xv[j]);
            *(s16x8*)&X_l[row*64 + ((ch*8) ^ ((row&7)<<3))] = xb;
            float po = 0.f, pt = 0.f;
            #pragma unroll
            for (int j = 0; j < 8; ++j) {
                po = fmaf(xv[j], Wom_l[ch*8 + j], po);
                pt = fmaf(xv[j], Wth_l[ch*8 + j], pt);
            }
            po += __shfl_xor(po, 1, 64); pt += __shfl_xor(pt, 1, 64);
            po += __shfl_xor(po, 2, 64); pt += __shfl_xor(pt, 2, 64);
            po += __shfl_xor(po, 4, 64); pt += __shfl_xor(pt, 4, 64);
            if (ch == 0 && s < S_) {
                om[(size_t)bh*S_ + s] = po + bomv;
                float si, co;
                sincosf(pt + bthv, &si, &co);
                reinterpret_cast<float2*>(zp)[(size_t)bh*S_ + s] = make_float2(co, si);
            }
        }
        __syncthreads();
        int arow = w*16 + c;
        s16x8 xa0 = *(const s16x8*)&X_l[arow*64 + ((g*8)      ^ ((arow&7)<<3))];
        s16x8 xa1 = *(const s16x8*)&X_l[arow*64 + ((g*8 + 32) ^ ((arow&7)<<3))];

        const short* WT[3] = {WqT, WkT, WvT};
        short* dst[3] = {qh, kh, vh};
        #pragma unroll
        for (int o = 0; o < 3; ++o) {
            f32x4 acc[4];
            #pragma unroll
            for (int e4 = 0; e4 < 4; ++e4) {
                int brow = e4*16 + c;
                s16x8 b0 = *(const s16x8*)&WT[o][brow*64 + ((g*8)      ^ ((brow&7)<<3))];
                s16x8 b1 = *(const s16x8*)&WT[o][brow*64 + ((g*8 + 32) ^ ((brow&7)<<3))];
                f32x4 a = {0.f,0.f,0.f,0.f};
                a = __builtin_amdgcn_mfma_f32_16x16x32_bf16(xa0, b0, a, 0, 0, 0);
                a = __builtin_amdgcn_mfma_f32_16x16x32_bf16(xa1, b1, a, 0, 0, 0);
                acc[e4] = a;
            }
            float* bias = (o == 0) ? bqv : (o == 1) ? bkv : bvv;
            #pragma unroll
            for (int r = 0; r < 4; ++r) {
                int s = s0 + w*16 + 4*g + r;
                if (s < S_) {
                    s16x4 pk;
                    pk[0] = f2bf(acc[0][r] + bias[0]);
                    pk[1] = f2bf(acc[1][r] + bias[1]);
                    pk[2] = f2bf(acc[2][r] + bias[2]);
                    pk[3] = f2bf(acc[3][r] + bias[3]);
                    *(s16x4*)(dst[o] + (size_t)bh*S_*DH + (size_t)s*DH + c*4) = pk;
                }
            }
        }
    }
}

// ---------------------------------------------------------------------------
// K2: Stuart-Landau ODE, LDS-resident bf16 k/q, 16 waves (REVERT to the
// validated r14 structure — 3 rounds of evidence show the register-resident
// variant is allocator-capped at 64 VGPR and spills 1.2 GB to scratch).
// Only merge: the 16-shfl kz redistribute is replaced by the kzv[64] LDS
// round-trip (proven same-wave RAW pattern, ran correctly in r15-r17).
// ---------------------------------------------------------------------------
__global__ __launch_bounds__(1024) void k_ode(
    const short* __restrict__ qh, const short* __restrict__ kh,
    const float* __restrict__ om,
    const float* __restrict__ mu, const float* __restrict__ kappa,
    const float* __restrict__ alpha, const int* __restrict__ nsim,
    float* __restrict__ zp)
{
    __shared__ __align__(16) unsigned kp_l[64*KPR];   // 75,008 B
    __shared__ __align__(16) short    q_l[S_*64];     // 73,856 B
    __shared__ __align__(16) float2   z_l[584];       // 4,672 B
    __shared__ __align__(16) float2   z1_l[584];      // 4,672 B
    __shared__ __align__(16) float2   kz_s[8][64];    // 4,096 B
    __shared__ __align__(16) float2   kzv[64];        // 512 B  (162,816 total)

    int bh = blockIdx.x, h = bh & 15;
    int tid = threadIdx.x, w = tid >> 6, lane = tid & 63;
    const short* kg = kh + (size_t)bh*S_*DH;
    const short* qg = qh + (size_t)bh*S_*DH;
    float2* zpg = reinterpret_cast<float2*>(zp) + (size_t)bh*S_;
    const float* omg = om + (size_t)bh*S_;

    for (int i = tid; i < 584; i += 1024) {
        z_l[i] = (i < S_) ? zpg[i] : make_float2(0.f, 0.f);
        z1_l[i] = make_float2(0.f, 0.f);
    }
    {
        int e0 = (tid & 7) * 8;
        for (int sp = tid >> 3; sp < SPP; sp += 128) {
            int sA = 2*sp, sB = 2*sp + 1;
            s16x8 ka = {0,0,0,0,0,0,0,0}, kb = ka;
            if (sA < S_) ka = *(const s16x8*)(kg + (size_t)sA*DH + e0);
            if (sB < S_) kb = *(const s16x8*)(kg + (size_t)sB*DH + e0);
            #pragma unroll
            for (int j = 0; j < 8; ++j)
                kp_l[(e0+j)*KPR + sp] =
                    ((unsigned)(unsigned short)ka[j]) |
                    (((unsigned)(unsigned short)kb[j]) << 16);
        }
    }
    for (int cid = tid; cid < S_*8; cid += 1024) {
        int s = cid >> 3, c = cid & 7;
        s16x8 v = *(const s16x8*)(qg + (size_t)s*DH + c*8);
        *(s16x8*)&q_l[s*64 + ((c*8) ^ ((s&7)<<3))] = v;
    }
    int i8 = lane >> 3, d0 = (lane & 7) << 3;
    int s0 = w * SPW2;
    float om_r[5];
    #pragma unroll
    for (int m2 = 0; m2 < 5; ++m2) {
        int li = i8 + 8*m2, s = s0 + li;
        om_r[m2] = (li < SPW2 && s < S_) ? omg[s] : 0.f;
    }
    float ca = cosf(alpha[h]), sa = sinf(alpha[h]);
    float muv = mu[h];
    float cc = kappa[h] * SCALE_ / (float)S_;
    int NT = nsim[0];
    int sp0 = (w * SPP) >> 4, spE = ((w + 1) * SPP) >> 4;
    __syncthreads();

    for (int ev = 0; ev < 2*NT; ++ev) {
        bool second = ev & 1;
        const float2* zin = second ? z1_l : z_l;
        // phase A: partial kz[e=lane] over this wave's sp-slice
        float ar = 0.f, ai = 0.f, br = 0.f, bi = 0.f;
        for (int sp = sp0; sp < spE; ++sp) {
            unsigned kv = kp_l[lane*KPR + sp];
            float4 zz = *reinterpret_cast<const float4*>(&zin[2*sp]);
            float klo = __builtin_bit_cast(float, kv << 16);
            float khi = __builtin_bit_cast(float, kv & 0xffff0000u);
            ar = fmaf(klo, zz.x, ar); ai = fmaf(klo, zz.y, ai);
            br = fmaf(khi, zz.z, br); bi = fmaf(khi, zz.w, bi);
        }
        float2 part = make_float2(ar + br, ai + bi);
        if (w < 8) kz_s[w][lane] = part;
        __syncthreads();
        if (w >= 8) {
            float2 t = kz_s[w - 8][lane];
            t.x += part.x; t.y += part.y;
            kz_s[w - 8][lane] = t;
        }
        __syncthreads();
        // every lane computes kz[e=lane], writes kzv[lane]; then reads its
        // 8 needed entries as broadcast b128 (same-wave RAW only; the next
        // write to kzv is separated by the end-of-eval barrier + fold barriers)
        {
            float sr = 0.f, si = 0.f;
            #pragma unroll
            for (int w2 = 0; w2 < 8; ++w2) {
                float2 t = kz_s[w2][lane];
                sr += t.x; si += t.y;
            }
            kzv[lane] = make_float2(sr, si);
        }
        float4 kza = *reinterpret_cast<const float4*>(&kzv[d0]);
        float4 kzb = *reinterpret_cast<const float4*>(&kzv[d0 + 2]);
        float4 kzc = *reinterpret_cast<const float4*>(&kzv[d0 + 4]);
        float4 kzd = *reinterpret_cast<const float4*>(&kzv[d0 + 6]);
        float kzr[8] = {kza.x, kza.z, kzb.x, kzb.z, kzc.x, kzc.z, kzd.x, kzd.z};
        float kzi[8] = {kza.y, kza.w, kzb.y, kzb.w, kzc.y, kzc.w, kzd.y, kzd.w};
        // phase B: u_s = cc * q_s . kz ; Stuart-Landau + Heun
        #pragma unroll
        for (int m2 = 0; m2 < 5; ++m2) {
            int li = i8 + 8*m2, s = s0 + li;
            bool act = (li < SPW2) && (s < S_);
            int sq = (s <= S_-1) ? s : S_-1;
            s16x8 qv = *(const s16x8*)&q_l[sq*64 + (d0 ^ ((sq&7)<<3))];
            float ur = 0.f, ui = 0.f;
            #pragma unroll
            for (int j = 0; j < 8; ++j) {
                float qf = bf2f(qv[j]);
                ur = fmaf(qf, kzr[j], ur);
                ui = fmaf(qf, kzi[j], ui);
            }
            #pragma unroll
            for (int mm = 1; mm < 8; mm <<= 1) {
                ur += __shfl_xor(ur, mm, 64);
                ui += __shfl_xor(ui, mm, 64);
            }
            if (act && d0 == 0) {
                float2 z = zin[s];
                float urc = cc*ur, uic = cc*ui;
                float cr = ca*urc + sa*uic;
                float ci = ca*uic - sa*urc;
                float g = muv - (z.x*z.x + z.y*z.y);
                float dr = fmaf(g, z.x, fmaf(-om_r[m2], z.y, cr));
                float di = fmaf(g, z.y, fmaf( om_r[m2], z.x, ci));
                float2 zb = z_l[s];
                if (!second) {
                    z1_l[s] = make_float2(fmaf(DT_, dr, z.x), fmaf(DT_, di, z.y));
                    z_l[s]  = make_float2(fmaf(0.5f*DT_, dr, zb.x), fmaf(0.5f*DT_, di, zb.y));
                } else {
                    z_l[s]  = make_float2(fmaf(0.5f*DT_, dr, zb.x), fmaf(0.5f*DT_, di, zb.y));
                }
            }
        }
        __syncthreads();
    }
    for (int i = tid; i < S_; i += 1024) zpg[i] = z_l[i];
}

// ---------------------------------------------------------------------------
// K3: dual flash attention. (unchanged, validated r13/r14)
// ---------------------------------------------------------------------------
__global__ __launch_bounds__(512) void k_attn(
    const short* __restrict__ qh, const short* __restrict__ kh,
    const short* __restrict__ vh, const float* __restrict__ zp,
    const float* __restrict__ mix_logit, const float* __restrict__ band_logits,
    short* __restrict__ yh)
{
    __shared__ short q_l[128*64];     // q (prologue+hoist), then P0 slices
    __shared__ short P1_l[8][1024];   // resonance-branch P
    __shared__ short k_l2[64*64];
    __shared__ short vT_l[64*64];
    __shared__ float2 zs_l[128];
    __shared__ float2 zt_l[64];

    int blk = blockIdx.x;
    int bh = blk / 5, rc = blk - bh*5;
    int b = bh >> 4, h = bh & 15;
    int r0 = rc * 128;
    int tid = threadIdx.x, w = tid >> 6, lane = tid & 63;
    int c = lane & 15, g = lane >> 4;

    const short* qg = qh + (size_t)bh*S_*DH;
    const short* kg = kh + (size_t)bh*S_*DH;
    const short* vg = vh + (size_t)bh*S_*DH;
    const float2* zpg = (const float2*)zp + (size_t)bh*S_;

    #pragma unroll
    for (int i = 0; i < 2; ++i) {
        int cid = tid + 512*i;
        int row = cid >> 3, ch = cid & 7;
        int s = r0 + row;
        s16x8 val = {0,0,0,0,0,0,0,0};
        if (s < S_) val = *(const s16x8*)(qg + (size_t)s*DH + ch*8);
        *(s16x8*)&q_l[row*64 + ((ch*8) ^ ((row&7)<<3))] = val;
    }
    if (tid < 128) {
        float2 z = (r0 + tid < S_) ? zpg[r0 + tid] : make_float2(0.f,0.f);
        zs_l[tid] = make_float2(z.x*(BETA_*L2E), z.y*(BETA_*L2E));
    }
    __syncthreads();

    s16x8 qf0, qf1;
    {
        int row = w*16 + c;
        qf0 = *(const s16x8*)&q_l[row*64 + ((g*8)      ^ ((row&7)<<3))];
        qf1 = *(const s16x8*)&q_l[row*64 + ((g*8 + 32) ^ ((row&7)<<3))];
    }
    float2 zsr[4];
    #pragma unroll
    for (int r = 0; r < 4; ++r) zsr[r] = zs_l[w*16 + (g<<2) + r];

    f32x4 accv[4], accr[4];
    float Z_v[4], Z_r[4];
    #pragma unroll
    for (int i = 0; i < 4; ++i) {
        accv[i] = (f32x4){0.f,0.f,0.f,0.f};
        accr[i] = (f32x4){0.f,0.f,0.f,0.f};
        Z_v[i] = 0.f; Z_r[i] = 0.f;
    }

    short* P0 = &q_l[w << 10];   // per-wave 1024-short slice (dead q space)
    short* P1 = &P1_l[w][0];

    for (int tt = 0; tt < 10; ++tt) {
        int t0g = tt * 64;
        __syncthreads();
        {   // stage k tile (stored-e space, same as q)
            int row = tid >> 3, ch = tid & 7;
            int t = t0g + row;
            s16x8 val = {0,0,0,0,0,0,0,0};
            if (t < S_) val = *(const s16x8*)(kg + (size_t)t*DH + ch*8);
            *(s16x8*)&k_l2[row*64 + ((ch*8) ^ ((row&7)<<3))] = val;
        }
        {   // stage v: stored col -> TRUE e row, perm'd k-cols, vswz banks
            int tloc = tid >> 3, d0 = (tid & 7) << 3;
            int pt = ((tloc & 15) << 2) + (tloc >> 4);   // perm(t)
            s16x8 vv = {0,0,0,0,0,0,0,0};
            if (t0g + tloc < S_) vv = *(const s16x8*)(vg + (size_t)(t0g+tloc)*DH + d0);
            #pragma unroll
            for (int j = 0; j < 8; ++j) {
                int sc = d0 + j;                          // stored col
                int te = ((sc & 3) << 4) + (sc >> 2);     // true e
                vT_l[te*64 + (pt ^ vswz(te))] = vv[j];
            }
        }
        if (tid < 64) zt_l[tid] = (t0g + tid < S_) ? zpg[t0g + tid] : make_float2(0.f,0.f);
        __syncthreads();

        // ---- scores (exp2 domain)
        f32x4 sv[4], sr4[4];
        #pragma unroll
        for (int sub = 0; sub < 4; ++sub) {
            int row = sub*16 + c;
            s16x8 kf0 = *(const s16x8*)&k_l2[row*64 + ((g*8)      ^ ((c&7)<<3))];
            s16x8 kf1 = *(const s16x8*)&k_l2[row*64 + ((g*8 + 32) ^ ((c&7)<<3))];
            f32x4 a = {0.f,0.f,0.f,0.f};
            a = __builtin_amdgcn_mfma_f32_16x16x32_bf16(qf0, kf0, a, 0, 0, 0);
            a = __builtin_amdgcn_mfma_f32_16x16x32_bf16(qf1, kf1, a, 0, 0, 0);
            sv[sub] = a * (SCALE_ * L2E) - OFFV2;
        }
        #pragma unroll
        for (int sub = 0; sub < 4; ++sub) {
            float2 zt = zt_l[sub*16 + c];
            #pragma unroll
            for (int r = 0; r < 4; ++r)
                sr4[sub][r] = fmaf(zsr[r].x, zt.x, fmaf(zsr[r].y, zt.y, -OFFR2));
        }
        if (t0g + 64 > S_) {    // uniform: only the tail tile
            #pragma unroll
            for (int sub = 0; sub < 4; ++sub)
                if (t0g + sub*16 + c >= S_) {
                    #pragma unroll
                    for (int r = 0; r < 4; ++r) { sv[sub][r] = -1e30f; sr4[sub][r] = -1e30f; }
                }
        }

        // ---- softmax numerators: exp2 + RNE f2bf, one b64 store per (r,branch)
        #pragma unroll
        for (int r = 0; r < 4; ++r) {
            int sl = (g<<2) + r;
            int pco = sl*64 + ((c*4) ^ ((sl&7)<<3));   // perm(t)=c*4+sub cols
            s16x4 pk0, pk1;
            float sumv = 0.f, sumr = 0.f;
            #pragma unroll
            for (int sub = 0; sub < 4; ++sub) {
                float pv = ex2(sv[sub][r]);
                float pr = ex2(sr4[sub][r]);
                sumv += pv; sumr += pr;
                pk0[sub] = f2bf(pv);
                pk1[sub] = f2bf(pr);
            }
            *(s16x4*)&P0[pco] = pk0;
            *(s16x4*)&P1[pco] = pk1;
            Z_v[r] += sumv;
            Z_r[r] += sumr;
        }

        // ---- PV: read both branches (read-once per tile)
        #pragma unroll
        for (int hh = 0; hh < 2; ++hh) {
            int kc = g*8 + 32*hh;
            int po = c*64 + (kc ^ ((c&7)<<3));
            s16x8 pa_v = *(const s16x8*)&P0[po];
            s16x8 pa_r = *(const s16x8*)&P1[po];
            #pragma unroll
            for (int d = 0; d < 4; ++d) {
                int row = d*16 + c;
                s16x8 vf = *(const s16x8*)&vT_l[row*64 + (kc ^ vswz(row))];
                accv[d] = __builtin_amdgcn_mfma_f32_16x16x32_bf16(pa_v, vf, accv[d], 0, 0, 0);
                accr[d] = __builtin_amdgcn_mfma_f32_16x16x32_bf16(pa_r, vf, accr[d], 0, 0, 0);
            }
        }
    }

    // ---- single final Z reduce over the 16-lane c-group
    #pragma unroll
    for (int mm = 1; mm < 16; mm <<= 1) {
        #pragma unroll
        for (int r = 0; r < 4; ++r) {
            Z_v[r] += __shfl_xor(Z_v[r], mm, 64);
            Z_r[r] += __shfl_xor(Z_r[r], mm, 64);
        }
    }

    float mixv = 1.f/(1.f + __expf(-mix_logit[h]));
    #pragma unroll
    for (int d = 0; d < 4; ++d) {
        float gate = 1.f/(1.f + __expf(-band_logits[h*4 + d]));
        #pragma unroll
        for (int r = 0; r < 4; ++r) {
            int s = r0 + w*16 + (g<<2) + r;
            if (s < S_) {
                float val = mixv*gate*(accr[d][r]/Z_r[r]) + (1.f-mixv)*(accv[d][r]/Z_v[r]);
                yh[(size_t)b*S_*DM + (size_t)s*DM + h*DH + d*16 + c] = f2bf(val);
            }
        }
    }
}

// ---------------------------------------------------------------------------
// K4b: Wo (f32 [k][n]) -> WoT (bf16 [n][k]) tile transpose
// ---------------------------------------------------------------------------
__global__ __launch_bounds__(256) void k_cvt(
    const float* __restrict__ Wo, short* __restrict__ Bt)
{
    __shared__ short tl[64][65];
    int k0 = blockIdx.x * 64, n0 = blockIdx.y * 64;
    int tid = threadIdx.x;
    int r = tid >> 2, cb = (tid & 3) * 16;
    #pragma unroll
    for (int j4 = 0; j4 < 4; ++j4) {
        float4 v = *reinterpret_cast<const float4*>(Wo + (size_t)(k0+r)*1024 + n0 + cb + j4*4);
        tl[r][cb + j4*4 + 0] = f2bf(v.x);
        tl[r][cb + j4*4 + 1] = f2bf(v.y);
        tl[r][cb + j4*4 + 2] = f2bf(v.z);
        tl[r][cb + j4*4 + 3] = f2bf(v.w);
    }
    __syncthreads();
    s16x8 v0, v1;
    #pragma unroll
    for (int j = 0; j < 8; ++j) { v0[j] = tl[cb+j][r]; v1[j] = tl[cb+8+j][r]; }
    *(s16x8*)(Bt + (size_t)(n0+r)*1024 + k0 + cb)     = v0;
    *(s16x8*)(Bt + (size_t)(n0+r)*1024 + k0 + cb + 8) = v1;
}

// ---------------------------------------------------------------------------
// K4: out = y(9232x1024 bf16) @ Wo + bo, MFMA 16x16x32 bf16, 128x128 tile.
// ---------------------------------------------------------------------------
__global__ __launch_bounds__(256) void k_gemm(
    const short* __restrict__ A, const short* __restrict__ Bt,
    const float* __restrict__ bias, float* __restrict__ out)
{
    const int M = B_ * S_;
    __shared__ short A_l[128*64];
    __shared__ short B_l[128*64];
    int m0 = blockIdx.x * 128, n0 = blockIdx.y * 128;
    int tid = threadIdx.x, w = tid >> 6, lane = tid & 63;
    int c = lane & 15, g = lane >> 4;
    int mb = (w & 1) * 64, nb = (w >> 1) * 64;
    f32x4 acc[4][4];
    #pragma unroll
    for (int i = 0; i < 4; ++i)
        #pragma unroll
        for (int j = 0; j < 4; ++j) acc[i][j] = (f32x4){0.f,0.f,0.f,0.f};
    for (int k0 = 0; k0 < 1024; k0 += 64) {
        __syncthreads();
        #pragma unroll
        for (int i = 0; i < 4; ++i) {
            int cid = tid + 256*i;
            int row = cid >> 3, ch = cid & 7;
            int m = m0 + row;
            s16x8 av = {0,0,0,0,0,0,0,0};
            if (m < M) av = *(const s16x8*)(A + (size_t)m*1024 + k0 + ch*8);
            *(s16x8*)&A_l[row*64 + ((ch*8) ^ ((row&7)<<3))] = av;
            s16x8 bv = *(const s16x8*)(Bt + (size_t)(n0+row)*1024 + k0 + ch*8);
            *(s16x8*)&B_l[row*64 + ((ch*8) ^ ((row&7)<<3))] = bv;
        }
        __syncthreads();
        s16x8 af[4][2], bf[4][2];
        #pragma unroll
        for (int i = 0; i < 4; ++i) {
            int ra = mb + i*16 + c;
            af[i][0] = *(const s16x8*)&A_l[ra*64 + ((g*8)      ^ ((c&7)<<3))];
            af[i][1] = *(const s16x8*)&A_l[ra*64 + ((g*8 + 32) ^ ((c&7)<<3))];
            int rb = nb + i*16 + c;
            bf[i][0] = *(const s16x8*)&B_l[rb*64 + ((g*8)      ^ ((c&7)<<3))];
            bf[i][1] = *(const s16x8*)&B_l[rb*64 + ((g*8 + 32) ^ ((c&7)<<3))];
        }
        #pragma unroll
        for (int i = 0; i < 4; ++i)
            #pragma unroll
            for (int j = 0; j < 4; ++j) {
                acc[i][j] = __builtin_amdgcn_mfma_f32_16x16x32_bf16(af[i][0], bf[j][0], acc[i][j], 0, 0, 0);
                acc[i][j] = __builtin_amdgcn_mfma_f32_16x16x32_bf16(af[i][1], bf[j][1], acc[i][j], 0, 0, 0);
            }
    }
    #pragma unroll
    for (int j = 0; j < 4; ++j) {
        float bv = bias[n0 + nb + j*16 + c];
        #pragma unroll
        for (int i = 0; i < 4; ++i)
            #pragma unroll
            for (int r = 0; r < 4; ++r) {
                int m = m0 + mb + i*16 + 4*g + r;
                if (m < M) out[(size_t)m*1024 + n0 + nb + j*16 + c] = acc[i][j][r] + bv;
            }
    }
}

// ---------------------------------------------------------------------------
extern "C" void kernel_launch(void* const* d_in, const int* in_sizes, int n_in,
                              void* d_out, int out_size, void* d_ws, size_t ws_size,
                              hipStream_t stream)
{
    const float* x   = (const float*)d_in[0];
    const float* Wq  = (const float*)d_in[1];
    const float* bq  = (const float*)d_in[2];
    const float* Wk  = (const float*)d_in[3];
    const float* bk  = (const float*)d_in[4];
    const float* Wv  = (const float*)d_in[5];
    const float* bv  = (const float*)d_in[6];
    const float* Wom = (const float*)d_in[7];
    const float* bom = (const float*)d_in[8];
    const float* Wth = (const float*)d_in[9];
    const float* bth = (const float*)d_in[10];
    const float* mu  = (const float*)d_in[11];
    const float* kap = (const float*)d_in[12];
    const float* alp = (const float*)d_in[13];
    const float* mix = (const float*)d_in[14];
    const float* bl  = (const float*)d_in[15];
    const float* Wo  = (const float*)d_in[16];
    const float* bo  = (const float*)d_in[17];
    const int* nsim  = (const int*)d_in[18];

    float* ws = (float*)d_ws;
    const size_t QKV = (size_t)BH_ * S_ * DH;    // 9,453,568
    float* qf = ws;                               // slot A (aliased below)
    float* kf = qf + QKV;                         // slot B (aliased below)
    float* om = kf + QKV;                         // BH*S
    float* zp = om + (size_t)BH_*S_;              // 2*BH*S
    short* qh = (short*)(zp + (size_t)2*BH_*S_);  // bf16 q (e-permuted)
    short* kh = qh + QKV;                         // bf16 k (e-permuted)
    short* vh = kh + QKV;                         // bf16 v (e-permuted)
    short* yh  = (short*)qf;                      // bf16 y (attn out)
    short* WoT = (short*)kf;                      // bf16 Wo^T
    float* outf = (float*)d_out;

    k_proj<<<BH_, 512, 0, stream>>>(x, Wq, bq, Wk, bk, Wv, bv, Wom, bom, Wth, bth,
                                    qh, kh, vh, om, zp);
    k_ode<<<BH_, 1024, 0, stream>>>(qh, kh, om, mu, kap, alp, nsim, zp);
    k_cvt<<<dim3(16,16), 256, 0, stream>>>(Wo, WoT);
    k_attn<<<BH_*5, 512, 0, stream>>>(qh, kh, vh, zp, mix, bl, yh);
    dim3 gg(73, 8);
    k_gemm<<<gg, 256, 0, stream>>>(yh, WoT, bo, outf);
}

// Round 19
// 291.660 us; speedup vs baseline: 2.1534x; 1.0779x over previous
//
#include <hip/hip_runtime.h>
#include <hip/hip_bf16.h>

#define S_ 577
#define B_ 16
#define H_ 16
#define DH 64
#define DM 1024
#define BH_ 256
#define DT_ 0.01f
#define BETA_ 4.0f
#define SCALE_ 0.125f
#define SPP 292     // s-pairs in k_ode phase A
#define KPR 293     // k_ode kp row stride (odd -> conflict-free)
#define SPW2 37     // s-rows per wave (k_ode phase B, 16 waves)
#define L2E 1.44269504f
#define OFFV2 (4.0f * L2E)   // static exp2 offset, vanilla
#define OFFR2 (6.0f * L2E)   // static exp2 offset, resonance

typedef float f32x4 __attribute__((ext_vector_type(4)));
typedef short s16x8 __attribute__((ext_vector_type(8)));
typedef short s16x4 __attribute__((ext_vector_type(4)));

__device__ inline short f2bf(float x) {     // RNE f32->bf16 (PROVEN; v_cvt_pk_bf16_f32 is NOT RNE on gfx950 — r6/r12 failures)
    unsigned b = __builtin_bit_cast(unsigned, x);
    b += 0x7fffu + ((b >> 16) & 1u);
    return (short)(b >> 16);
}
__device__ inline float bf2f(short s) {
    unsigned u = ((unsigned)(unsigned short)s) << 16;
    return __builtin_bit_cast(float, u);
}
__device__ inline float ex2(float x) {     // 2^x (v_exp_f32 per ISA)
    float r;
    asm("v_exp_f32 %0, %1" : "=v"(r) : "v"(x));
    return r;
}
// async global->LDS, 16B per lane; dest must be linear (base + lane*16)
__device__ inline void gload16(const void* g, void* l) {
    __builtin_amdgcn_global_load_lds(
        (const __attribute__((address_space(1))) unsigned int*)g,
        (__attribute__((address_space(3))) unsigned int*)l, 16, 0, 0);
}
// vT bank-spreading swizzle (write & read use the same formula of row)
__device__ inline int vswz(int row) { return (((row >> 3) ^ row) & 7) << 3; }

// ---------------------------------------------------------------------------
// K1: per-(b,h) projections via MFMA. (unchanged, validated r13/r14/r18)
// ---------------------------------------------------------------------------
__global__ __launch_bounds__(512) void k_proj(
    const float* __restrict__ x,
    const float* __restrict__ Wq, const float* __restrict__ bq,
    const float* __restrict__ Wk, const float* __restrict__ bk,
    const float* __restrict__ Wv, const float* __restrict__ bv,
    const float* __restrict__ Wom, const float* __restrict__ bom,
    const float* __restrict__ Wth, const float* __restrict__ bth,
    short* __restrict__ qh, short* __restrict__ kh, short* __restrict__ vh,
    float* __restrict__ om, float* __restrict__ zp)
{
    __shared__ __align__(16) short WqT[64*64], WkT[64*64], WvT[64*64];
    __shared__ __align__(16) short X_l[128*64];
    __shared__ float Wom_l[64], Wth_l[64];

    int bh = blockIdx.x, b = bh >> 4, h = bh & 15;
    int tid = threadIdx.x, w = tid >> 6, lane = tid & 63;
    int c = lane & 15, g = lane >> 4;

    {
        int d = tid >> 3, e0 = (tid & 7) << 3;
        const float* pq = Wq + (size_t)h*4096 + d*64 + e0;
        const float* pk = Wk + (size_t)h*4096 + d*64 + e0;
        const float* pv = Wv + (size_t)h*4096 + d*64 + e0;
        float4 q0 = *(const float4*)pq, q1 = *(const float4*)(pq + 4);
        float4 k0 = *(const float4*)pk, k1 = *(const float4*)(pk + 4);
        float4 v0 = *(const float4*)pv, v1 = *(const float4*)(pv + 4);
        float qv[8] = {q0.x,q0.y,q0.z,q0.w,q1.x,q1.y,q1.z,q1.w};
        float kv[8] = {k0.x,k0.y,k0.z,k0.w,k1.x,k1.y,k1.z,k1.w};
        float vv[8] = {v0.x,v0.y,v0.z,v0.w,v1.x,v1.y,v1.z,v1.w};
        #pragma unroll
        for (int j = 0; j < 8; ++j) {
            int e = e0 + j;
            int off = e*64 + (d ^ ((e&7)<<3));
            WqT[off] = f2bf(qv[j]);
            WkT[off] = f2bf(kv[j]);
            WvT[off] = f2bf(vv[j]);
        }
    }
    if (tid < 64) { Wom_l[tid] = Wom[h*64 + tid]; Wth_l[tid] = Wth[h*64 + tid]; }

    float bqv[4], bkv[4], bvv[4];
    #pragma unroll
    for (int e4 = 0; e4 < 4; ++e4) {
        bqv[e4] = bq[h*64 + e4*16 + c];
        bkv[e4] = bk[h*64 + e4*16 + c];
        bvv[e4] = bv[h*64 + e4*16 + c];
    }
    float bomv = bom[h], bthv = bth[h];

    const size_t xbase = (size_t)b*S_*DM + (size_t)h*DH;

    for (int t5 = 0; t5 < 5; ++t5) {
        int s0 = t5 * 128;
        __syncthreads();
        #pragma unroll
        for (int i = 0; i < 2; ++i) {
            int cid = tid + 512*i;
            int row = cid >> 3, ch = cid & 7;
            int s = s0 + row;
            float xv[8];
            if (s < S_) {
                const float* px = x + xbase + (size_t)s*DM + ch*8;
                float4 a0 = *(const float4*)px, a1 = *(const float4*)(px + 4);
                xv[0]=a0.x; xv[1]=a0.y; xv[2]=a0.z; xv[3]=a0.w;
                xv[4]=a1.x; xv[5]=a1.y; xv[6]=a1.z; xv[7]=a1.w;
                #pragma unroll
                for (int j = 0; j < 8; ++j) if (!isfinite(xv[j])) xv[j] = 0.f;
            } else {
                #pragma unroll
                for (int j = 0; j < 8; ++j) xv[j] = 0.f;
            }
            s16x8 xb;
            #pragma unroll
            for (int j = 0; j < 8; ++j) xb[j] = f2bf(xv[j]);
            *(s16x8*)&X_l[row*64 + ((ch*8) ^ ((row&7)<<3))] = xb;
            float po = 0.f, pt = 0.f;
            #pragma unroll
            for (int j = 0; j < 8; ++j) {
                po = fmaf(xv[j], Wom_l[ch*8 + j], po);
                pt = fmaf(xv[j], Wth_l[ch*8 + j], pt);
            }
            po += __shfl_xor(po, 1, 64); pt += __shfl_xor(pt, 1, 64);
            po += __shfl_xor(po, 2, 64); pt += __shfl_xor(pt, 2, 64);
            po += __shfl_xor(po, 4, 64); pt += __shfl_xor(pt, 4, 64);
            if (ch == 0 && s < S_) {
                om[(size_t)bh*S_ + s] = po + bomv;
                float si, co;
                sincosf(pt + bthv, &si, &co);
                reinterpret_cast<float2*>(zp)[(size_t)bh*S_ + s] = make_float2(co, si);
            }
        }
        __syncthreads();
        int arow = w*16 + c;
        s16x8 xa0 = *(const s16x8*)&X_l[arow*64 + ((g*8)      ^ ((arow&7)<<3))];
        s16x8 xa1 = *(const s16x8*)&X_l[arow*64 + ((g*8 + 32) ^ ((arow&7)<<3))];

        const short* WT[3] = {WqT, WkT, WvT};
        short* dst[3] = {qh, kh, vh};
        #pragma unroll
        for (int o = 0; o < 3; ++o) {
            f32x4 acc[4];
            #pragma unroll
            for (int e4 = 0; e4 < 4; ++e4) {
                int brow = e4*16 + c;
                s16x8 b0 = *(const s16x8*)&WT[o][brow*64 + ((g*8)      ^ ((brow&7)<<3))];
                s16x8 b1 = *(const s16x8*)&WT[o][brow*64 + ((g*8 + 32) ^ ((brow&7)<<3))];
                f32x4 a = {0.f,0.f,0.f,0.f};
                a = __builtin_amdgcn_mfma_f32_16x16x32_bf16(xa0, b0, a, 0, 0, 0);
                a = __builtin_amdgcn_mfma_f32_16x16x32_bf16(xa1, b1, a, 0, 0, 0);
                acc[e4] = a;
            }
            float* bias = (o == 0) ? bqv : (o == 1) ? bkv : bvv;
            #pragma unroll
            for (int r = 0; r < 4; ++r) {
                int s = s0 + w*16 + 4*g + r;
                if (s < S_) {
                    s16x4 pk;
                    pk[0] = f2bf(acc[0][r] + bias[0]);
                    pk[1] = f2bf(acc[1][r] + bias[1]);
                    pk[2] = f2bf(acc[2][r] + bias[2]);
                    pk[3] = f2bf(acc[3][r] + bias[3]);
                    *(s16x4*)(dst[o] + (size_t)bh*S_*DH + (size_t)s*DH + c*4) = pk;
                }
            }
        }
    }
}

// ---------------------------------------------------------------------------
// K2: Stuart-Landau ODE, LDS-resident bf16 k/q, 16 waves. (unchanged, r18)
// ---------------------------------------------------------------------------
__global__ __launch_bounds__(1024) void k_ode(
    const short* __restrict__ qh, const short* __restrict__ kh,
    const float* __restrict__ om,
    const float* __restrict__ mu, const float* __restrict__ kappa,
    const float* __restrict__ alpha, const int* __restrict__ nsim,
    float* __restrict__ zp)
{
    __shared__ __align__(16) unsigned kp_l[64*KPR];
    __shared__ __align__(16) short    q_l[S_*64];
    __shared__ __align__(16) float2   z_l[584];
    __shared__ __align__(16) float2   z1_l[584];
    __shared__ __align__(16) float2   kz_s[8][64];
    __shared__ __align__(16) float2   kzv[64];

    int bh = blockIdx.x, h = bh & 15;
    int tid = threadIdx.x, w = tid >> 6, lane = tid & 63;
    const short* kg = kh + (size_t)bh*S_*DH;
    const short* qg = qh + (size_t)bh*S_*DH;
    float2* zpg = reinterpret_cast<float2*>(zp) + (size_t)bh*S_;
    const float* omg = om + (size_t)bh*S_;

    for (int i = tid; i < 584; i += 1024) {
        z_l[i] = (i < S_) ? zpg[i] : make_float2(0.f, 0.f);
        z1_l[i] = make_float2(0.f, 0.f);
    }
    {
        int e0 = (tid & 7) * 8;
        for (int sp = tid >> 3; sp < SPP; sp += 128) {
            int sA = 2*sp, sB = 2*sp + 1;
            s16x8 ka = {0,0,0,0,0,0,0,0}, kb = ka;
            if (sA < S_) ka = *(const s16x8*)(kg + (size_t)sA*DH + e0);
            if (sB < S_) kb = *(const s16x8*)(kg + (size_t)sB*DH + e0);
            #pragma unroll
            for (int j = 0; j < 8; ++j)
                kp_l[(e0+j)*KPR + sp] =
                    ((unsigned)(unsigned short)ka[j]) |
                    (((unsigned)(unsigned short)kb[j]) << 16);
        }
    }
    for (int cid = tid; cid < S_*8; cid += 1024) {
        int s = cid >> 3, c = cid & 7;
        s16x8 v = *(const s16x8*)(qg + (size_t)s*DH + c*8);
        *(s16x8*)&q_l[s*64 + ((c*8) ^ ((s&7)<<3))] = v;
    }
    int i8 = lane >> 3, d0 = (lane & 7) << 3;
    int s0 = w * SPW2;
    float om_r[5];
    #pragma unroll
    for (int m2 = 0; m2 < 5; ++m2) {
        int li = i8 + 8*m2, s = s0 + li;
        om_r[m2] = (li < SPW2 && s < S_) ? omg[s] : 0.f;
    }
    float ca = cosf(alpha[h]), sa = sinf(alpha[h]);
    float muv = mu[h];
    float cc = kappa[h] * SCALE_ / (float)S_;
    int NT = nsim[0];
    int sp0 = (w * SPP) >> 4, spE = ((w + 1) * SPP) >> 4;
    __syncthreads();

    for (int ev = 0; ev < 2*NT; ++ev) {
        bool second = ev & 1;
        const float2* zin = second ? z1_l : z_l;
        float ar = 0.f, ai = 0.f, br = 0.f, bi = 0.f;
        for (int sp = sp0; sp < spE; ++sp) {
            unsigned kv = kp_l[lane*KPR + sp];
            float4 zz = *reinterpret_cast<const float4*>(&zin[2*sp]);
            float klo = __builtin_bit_cast(float, kv << 16);
            float khi = __builtin_bit_cast(float, kv & 0xffff0000u);
            ar = fmaf(klo, zz.x, ar); ai = fmaf(klo, zz.y, ai);
            br = fmaf(khi, zz.z, br); bi = fmaf(khi, zz.w, bi);
        }
        float2 part = make_float2(ar + br, ai + bi);
        if (w < 8) kz_s[w][lane] = part;
        __syncthreads();
        if (w >= 8) {
            float2 t = kz_s[w - 8][lane];
            t.x += part.x; t.y += part.y;
            kz_s[w - 8][lane] = t;
        }
        __syncthreads();
        {
            float sr = 0.f, si = 0.f;
            #pragma unroll
            for (int w2 = 0; w2 < 8; ++w2) {
                float2 t = kz_s[w2][lane];
                sr += t.x; si += t.y;
            }
            kzv[lane] = make_float2(sr, si);
        }
        float4 kza = *reinterpret_cast<const float4*>(&kzv[d0]);
        float4 kzb = *reinterpret_cast<const float4*>(&kzv[d0 + 2]);
        float4 kzc = *reinterpret_cast<const float4*>(&kzv[d0 + 4]);
        float4 kzd = *reinterpret_cast<const float4*>(&kzv[d0 + 6]);
        float kzr[8] = {kza.x, kza.z, kzb.x, kzb.z, kzc.x, kzc.z, kzd.x, kzd.z};
        float kzi[8] = {kza.y, kza.w, kzb.y, kzb.w, kzc.y, kzc.w, kzd.y, kzd.w};
        #pragma unroll
        for (int m2 = 0; m2 < 5; ++m2) {
            int li = i8 + 8*m2, s = s0 + li;
            bool act = (li < SPW2) && (s < S_);
            int sq = (s <= S_-1) ? s : S_-1;
            s16x8 qv = *(const s16x8*)&q_l[sq*64 + (d0 ^ ((sq&7)<<3))];
            float ur = 0.f, ui = 0.f;
            #pragma unroll
            for (int j = 0; j < 8; ++j) {
                float qf = bf2f(qv[j]);
                ur = fmaf(qf, kzr[j], ur);
                ui = fmaf(qf, kzi[j], ui);
            }
            #pragma unroll
            for (int mm = 1; mm < 8; mm <<= 1) {
                ur += __shfl_xor(ur, mm, 64);
                ui += __shfl_xor(ui, mm, 64);
            }
            if (act && d0 == 0) {
                float2 z = zin[s];
                float urc = cc*ur, uic = cc*ui;
                float cr = ca*urc + sa*uic;
                float ci = ca*uic - sa*urc;
                float g = muv - (z.x*z.x + z.y*z.y);
                float dr = fmaf(g, z.x, fmaf(-om_r[m2], z.y, cr));
                float di = fmaf(g, z.y, fmaf( om_r[m2], z.x, ci));
                float2 zb = z_l[s];
                if (!second) {
                    z1_l[s] = make_float2(fmaf(DT_, dr, z.x), fmaf(DT_, di, z.y));
                    z_l[s]  = make_float2(fmaf(0.5f*DT_, dr, zb.x), fmaf(0.5f*DT_, di, zb.y));
                } else {
                    z_l[s]  = make_float2(fmaf(0.5f*DT_, dr, zb.x), fmaf(0.5f*DT_, di, zb.y));
                }
            }
        }
        __syncthreads();
    }
    for (int i = tid; i < S_; i += 1024) zpg[i] = z_l[i];
}

// ---------------------------------------------------------------------------
// K3: dual flash attention. r18 structure; q and k staging now use
// global_load_lds (linear LDS dest + pre-swizzled global source chunk
// ch^(row&7); reads keep the XOR swizzle -> composes to identity).
// v staging keeps scatter + ZERO-FILL (pad-t columns must be exactly 0:
// P*NaN protection). Dropped q/k guards are safe: OOB reads stay inside
// d_ws; garbage reaches only masked rows (k: score = -1e30 assignment;
// q: dead output rows masked at epilogue).
// ---------------------------------------------------------------------------
__global__ __launch_bounds__(512) void k_attn(
    const short* __restrict__ qh, const short* __restrict__ kh,
    const short* __restrict__ vh, const float* __restrict__ zp,
    const float* __restrict__ mix_logit, const float* __restrict__ band_logits,
    short* __restrict__ yh)
{
    __shared__ __align__(16) short q_l[128*64];   // q (prologue+hoist), then P0
    __shared__ __align__(16) short P1_l[8][1024]; // resonance-branch P
    __shared__ __align__(16) short k_l2[64*64];
    __shared__ __align__(16) short vT_l[64*64];
    __shared__ float2 zs_l[128];
    __shared__ float2 zt_l[64];

    int blk = blockIdx.x;
    int bh = blk / 5, rc = blk - bh*5;
    int b = bh >> 4, h = bh & 15;
    int r0 = rc * 128;
    int tid = threadIdx.x, w = tid >> 6, lane = tid & 63;
    int c = lane & 15, g = lane >> 4;

    const short* qg = qh + (size_t)bh*S_*DH;
    const short* kg = kh + (size_t)bh*S_*DH;
    const short* vg = vh + (size_t)bh*S_*DH;
    const float2* zpg = (const float2*)zp + (size_t)bh*S_;

    // ---- q staging via global_load_lds (linear dest, pre-swizzled source)
    #pragma unroll
    for (int i = 0; i < 2; ++i) {
        int cid = tid + 512*i;
        int row = cid >> 3, ch = cid & 7;
        int chs = ch ^ (row & 7);
        gload16(qg + (size_t)(r0 + row)*DH + chs*8, &q_l[cid*8]);
    }
    if (tid < 128) {
        float2 z = (r0 + tid < S_) ? zpg[r0 + tid] : make_float2(0.f,0.f);
        zs_l[tid] = make_float2(z.x*(BETA_*L2E), z.y*(BETA_*L2E));
    }
    __syncthreads();

    s16x8 qf0, qf1;
    {
        int row = w*16 + c;
        qf0 = *(const s16x8*)&q_l[row*64 + ((g*8)      ^ ((row&7)<<3))];
        qf1 = *(const s16x8*)&q_l[row*64 + ((g*8 + 32) ^ ((row&7)<<3))];
    }
    float2 zsr[4];
    #pragma unroll
    for (int r = 0; r < 4; ++r) zsr[r] = zs_l[w*16 + (g<<2) + r];

    f32x4 accv[4], accr[4];
    float Z_v[4], Z_r[4];
    #pragma unroll
    for (int i = 0; i < 4; ++i) {
        accv[i] = (f32x4){0.f,0.f,0.f,0.f};
        accr[i] = (f32x4){0.f,0.f,0.f,0.f};
        Z_v[i] = 0.f; Z_r[i] = 0.f;
    }

    short* P0 = &q_l[w << 10];   // per-wave 1024-short slice (dead q space)
    short* P1 = &P1_l[w][0];

    for (int tt = 0; tt < 10; ++tt) {
        int t0g = tt * 64;
        __syncthreads();
        {   // stage k tile via global_load_lds (linear dest, pre-swz source)
            int row = tid >> 3, ch = tid & 7;
            int chs = ch ^ (row & 7);
            gload16(kg + (size_t)(t0g + row)*DH + chs*8, &k_l2[tid*8]);
        }
        {   // stage v: stored col -> TRUE e row, perm'd k-cols, vswz banks
            // (keeps zero-fill: pad-t columns MUST be 0 for PV)
            int tloc = tid >> 3, d0 = (tid & 7) << 3;
            int pt = ((tloc & 15) << 2) + (tloc >> 4);   // perm(t)
            s16x8 vv = {0,0,0,0,0,0,0,0};
            if (t0g + tloc < S_) vv = *(const s16x8*)(vg + (size_t)(t0g+tloc)*DH + d0);
            #pragma unroll
            for (int j = 0; j < 8; ++j) {
                int sc = d0 + j;                          // stored col
                int te = ((sc & 3) << 4) + (sc >> 2);     // true e
                vT_l[te*64 + (pt ^ vswz(te))] = vv[j];
            }
        }
        if (tid < 64) zt_l[tid] = (t0g + tid < S_) ? zpg[t0g + tid] : make_float2(0.f,0.f);
        __syncthreads();

        // ---- scores (exp2 domain)
        f32x4 sv[4], sr4[4];
        #pragma unroll
        for (int sub = 0; sub < 4; ++sub) {
            int row = sub*16 + c;
            s16x8 kf0 = *(const s16x8*)&k_l2[row*64 + ((g*8)      ^ ((c&7)<<3))];
            s16x8 kf1 = *(const s16x8*)&k_l2[row*64 + ((g*8 + 32) ^ ((c&7)<<3))];
            f32x4 a = {0.f,0.f,0.f,0.f};
            a = __builtin_amdgcn_mfma_f32_16x16x32_bf16(qf0, kf0, a, 0, 0, 0);
            a = __builtin_amdgcn_mfma_f32_16x16x32_bf16(qf1, kf1, a, 0, 0, 0);
            sv[sub] = a * (SCALE_ * L2E) - OFFV2;
        }
        #pragma unroll
        for (int sub = 0; sub < 4; ++sub) {
            float2 zt = zt_l[sub*16 + c];
            #pragma unroll
            for (int r = 0; r < 4; ++r)
                sr4[sub][r] = fmaf(zsr[r].x, zt.x, fmaf(zsr[r].y, zt.y, -OFFR2));
        }
        if (t0g + 64 > S_) {    // uniform: only the tail tile
            #pragma unroll
            for (int sub = 0; sub < 4; ++sub)
                if (t0g + sub*16 + c >= S_) {
                    #pragma unroll
                    for (int r = 0; r < 4; ++r) { sv[sub][r] = -1e30f; sr4[sub][r] = -1e30f; }
                }
        }

        // ---- softmax numerators: exp2 + RNE f2bf, one b64 store per (r,branch)
        #pragma unroll
        for (int r = 0; r < 4; ++r) {
            int sl = (g<<2) + r;
            int pco = sl*64 + ((c*4) ^ ((sl&7)<<3));   // perm(t)=c*4+sub cols
            s16x4 pk0, pk1;
            float sumv = 0.f, sumr = 0.f;
            #pragma unroll
            for (int sub = 0; sub < 4; ++sub) {
                float pv = ex2(sv[sub][r]);
                float pr = ex2(sr4[sub][r]);
                sumv += pv; sumr += pr;
                pk0[sub] = f2bf(pv);
                pk1[sub] = f2bf(pr);
            }
            *(s16x4*)&P0[pco] = pk0;
            *(s16x4*)&P1[pco] = pk1;
            Z_v[r] += sumv;
            Z_r[r] += sumr;
        }

        // ---- PV: read both branches (read-once per tile)
        #pragma unroll
        for (int hh = 0; hh < 2; ++hh) {
            int kc = g*8 + 32*hh;
            int po = c*64 + (kc ^ ((c&7)<<3));
            s16x8 pa_v = *(const s16x8*)&P0[po];
            s16x8 pa_r = *(const s16x8*)&P1[po];
            #pragma unroll
            for (int d = 0; d < 4; ++d) {
                int row = d*16 + c;
                s16x8 vf = *(const s16x8*)&vT_l[row*64 + (kc ^ vswz(row))];
                accv[d] = __builtin_amdgcn_mfma_f32_16x16x32_bf16(pa_v, vf, accv[d], 0, 0, 0);
                accr[d] = __builtin_amdgcn_mfma_f32_16x16x32_bf16(pa_r, vf, accr[d], 0, 0, 0);
            }
        }
    }

    // ---- single final Z reduce over the 16-lane c-group
    #pragma unroll
    for (int mm = 1; mm < 16; mm <<= 1) {
        #pragma unroll
        for (int r = 0; r < 4; ++r) {
            Z_v[r] += __shfl_xor(Z_v[r], mm, 64);
            Z_r[r] += __shfl_xor(Z_r[r], mm, 64);
        }
    }

    float mixv = 1.f/(1.f + __expf(-mix_logit[h]));
    #pragma unroll
    for (int d = 0; d < 4; ++d) {
        float gate = 1.f/(1.f + __expf(-band_logits[h*4 + d]));
        #pragma unroll
        for (int r = 0; r < 4; ++r) {
            int s = r0 + w*16 + (g<<2) + r;
            if (s < S_) {
                float val = mixv*gate*(accr[d][r]/Z_r[r]) + (1.f-mixv)*(accv[d][r]/Z_v[r]);
                yh[(size_t)b*S_*DM + (size_t)s*DM + h*DH + d*16 + c] = f2bf(val);
            }
        }
    }
}

// ---------------------------------------------------------------------------
// K4b: Wo (f32 [k][n]) -> WoT (bf16 [n][k]) tile transpose
// ---------------------------------------------------------------------------
__global__ __launch_bounds__(256) void k_cvt(
    const float* __restrict__ Wo, short* __restrict__ Bt)
{
    __shared__ short tl[64][65];
    int k0 = blockIdx.x * 64, n0 = blockIdx.y * 64;
    int tid = threadIdx.x;
    int r = tid >> 2, cb = (tid & 3) * 16;
    #pragma unroll
    for (int j4 = 0; j4 < 4; ++j4) {
        float4 v = *reinterpret_cast<const float4*>(Wo + (size_t)(k0+r)*1024 + n0 + cb + j4*4);
        tl[r][cb + j4*4 + 0] = f2bf(v.x);
        tl[r][cb + j4*4 + 1] = f2bf(v.y);
        tl[r][cb + j4*4 + 2] = f2bf(v.z);
        tl[r][cb + j4*4 + 3] = f2bf(v.w);
    }
    __syncthreads();
    s16x8 v0, v1;
    #pragma unroll
    for (int j = 0; j < 8; ++j) { v0[j] = tl[cb+j][r]; v1[j] = tl[cb+8+j][r]; }
    *(s16x8*)(Bt + (size_t)(n0+r)*1024 + k0 + cb)     = v0;
    *(s16x8*)(Bt + (size_t)(n0+r)*1024 + k0 + cb + 8) = v1;
}

// ---------------------------------------------------------------------------
// K4: out = y @ Wo + bo, MFMA 16x16x32 bf16, 128x128 tile. Staging via
// global_load_lds (linear dest + pre-swizzled source; reads unchanged).
// OOB m-rows read inside d_ws; garbage lands only in masked output rows.
// ---------------------------------------------------------------------------
__global__ __launch_bounds__(256) void k_gemm(
    const short* __restrict__ A, const short* __restrict__ Bt,
    const float* __restrict__ bias, float* __restrict__ out)
{
    const int M = B_ * S_;
    __shared__ __align__(16) short A_l[128*64];
    __shared__ __align__(16) short B_l[128*64];
    int m0 = blockIdx.x * 128, n0 = blockIdx.y * 128;
    int tid = threadIdx.x, w = tid >> 6, lane = tid & 63;
    int c = lane & 15, g = lane >> 4;
    int mb = (w & 1) * 64, nb = (w >> 1) * 64;
    f32x4 acc[4][4];
    #pragma unroll
    for (int i = 0; i < 4; ++i)
        #pragma unroll
        for (int j = 0; j < 4; ++j) acc[i][j] = (f32x4){0.f,0.f,0.f,0.f};
    for (int k0 = 0; k0 < 1024; k0 += 64) {
        __syncthreads();
        #pragma unroll
        for (int i = 0; i < 4; ++i) {
            int cid = tid + 256*i;
            int row = cid >> 3, ch = cid & 7;
            int chs = ch ^ (row & 7);
            gload16(A  + (size_t)(m0 + row)*1024 + k0 + chs*8, &A_l[cid*8]);
            gload16(Bt + (size_t)(n0 + row)*1024 + k0 + chs*8, &B_l[cid*8]);
        }
        __syncthreads();
        s16x8 af[4][2], bf[4][2];
        #pragma unroll
        for (int i = 0; i < 4; ++i) {
            int ra = mb + i*16 + c;
            af[i][0] = *(const s16x8*)&A_l[ra*64 + ((g*8)      ^ ((c&7)<<3))];
            af[i][1] = *(const s16x8*)&A_l[ra*64 + ((g*8 + 32) ^ ((c&7)<<3))];
            int rb = nb + i*16 + c;
            bf[i][0] = *(const s16x8*)&B_l[rb*64 + ((g*8)      ^ ((c&7)<<3))];
            bf[i][1] = *(const s16x8*)&B_l[rb*64 + ((g*8 + 32) ^ ((c&7)<<3))];
        }
        #pragma unroll
        for (int i = 0; i < 4; ++i)
            #pragma unroll
            for (int j = 0; j < 4; ++j) {
                acc[i][j] = __builtin_amdgcn_mfma_f32_16x16x32_bf16(af[i][0], bf[j][0], acc[i][j], 0, 0, 0);
                acc[i][j] = __builtin_amdgcn_mfma_f32_16x16x32_bf16(af[i][1], bf[j][1], acc[i][j], 0, 0, 0);
            }
    }
    #pragma unroll
    for (int j = 0; j < 4; ++j) {
        float bv = bias[n0 + nb + j*16 + c];
        #pragma unroll
        for (int i = 0; i < 4; ++i)
            #pragma unroll
            for (int r = 0; r < 4; ++r) {
                int m = m0 + mb + i*16 + 4*g + r;
                if (m < M) out[(size_t)m*1024 + n0 + nb + j*16 + c] = acc[i][j][r] + bv;
            }
    }
}

// ---------------------------------------------------------------------------
extern "C" void kernel_launch(void* const* d_in, const int* in_sizes, int n_in,
                              void* d_out, int out_size, void* d_ws, size_t ws_size,
                              hipStream_t stream)
{
    const float* x   = (const float*)d_in[0];
    const float* Wq  = (const float*)d_in[1];
    const float* bq  = (const float*)d_in[2];
    const float* Wk  = (const float*)d_in[3];
    const float* bk  = (const float*)d_in[4];
    const float* Wv  = (const float*)d_in[5];
    const float* bv  = (const float*)d_in[6];
    const float* Wom = (const float*)d_in[7];
    const float* bom = (const float*)d_in[8];
    const float* Wth = (const float*)d_in[9];
    const float* bth = (const float*)d_in[10];
    const float* mu  = (const float*)d_in[11];
    const float* kap = (const float*)d_in[12];
    const float* alp = (const float*)d_in[13];
    const float* mix = (const float*)d_in[14];
    const float* bl  = (const float*)d_in[15];
    const float* Wo  = (const float*)d_in[16];
    const float* bo  = (const float*)d_in[17];
    const int* nsim  = (const int*)d_in[18];

    float* ws = (float*)d_ws;
    const size_t QKV = (size_t)BH_ * S_ * DH;    // 9,453,568
    float* qf = ws;                               // slot A (aliased below)
    float* kf = qf + QKV;                         // slot B (aliased below)
    float* om = kf + QKV;                         // BH*S
    float* zp = om + (size_t)BH_*S_;              // 2*BH*S
    short* qh = (short*)(zp + (size_t)2*BH_*S_);  // bf16 q (e-permuted)
    short* kh = qh + QKV;                         // bf16 k (e-permuted)
    short* vh = kh + QKV;                         // bf16 v (e-permuted)
    short* yh  = (short*)qf;                      // bf16 y (attn out)
    short* WoT = (short*)kf;                      // bf16 Wo^T
    float* outf = (float*)d_out;

    k_proj<<<BH_, 512, 0, stream>>>(x, Wq, bq, Wk, bk, Wv, bv, Wom, bom, Wth, bth,
                                    qh, kh, vh, om, zp);
    k_ode<<<BH_, 1024, 0, stream>>>(qh, kh, om, mu, kap, alp, nsim, zp);
    k_cvt<<<dim3(16,16), 256, 0, stream>>>(Wo, WoT);
    k_attn<<<BH_*5, 512, 0, stream>>>(qh, kh, vh, zp, mix, bl, yh);
    dim3 gg(73, 8);
    k_gemm<<<gg, 256, 0, stream>>>(yh, WoT, bo, outf);
}